// Round 10
// baseline (296.059 us; speedup 1.0000x reference)
//
#include <hip/hip_runtime.h>
#include <math.h>

#define N 512
#define NN (N*N)
#define D 128
#define DD (D*D)
#define ND (N*D)
#define GRID 288
#define SPIN_CAP (1 << 22)   // ~0.2s cap: converts any hang into a reported wrong-answer

typedef unsigned long long u64;
typedef unsigned uint32;

__device__ __forceinline__ float sigmoidf_(float x) { return 1.f / (1.f + expf(-x)); }

// ---- LLC-routed loads for cross-block intermediates (proven R6/R7).
__device__ __forceinline__ float ld_f(const float* p) {
    uint32 u = __hip_atomic_load((const uint32*)p, __ATOMIC_RELAXED, __HIP_MEMORY_SCOPE_AGENT);
    union { uint32 u; float f; } c; c.u = u; return c.f;
}
__device__ __forceinline__ float2 ld_f2(const float* p) {
    u64 u = __hip_atomic_load((const u64*)p, __ATOMIC_RELAXED, __HIP_MEMORY_SCOPE_AGENT);
    union { u64 u; float2 f; } c; c.u = u; return c.f;
}
__device__ __forceinline__ float4 ld_f4(const float* p) {
    float2 a = ld_f2(p), b = ld_f2(p + 2);
    return make_float4(a.x, a.y, b.x, b.y);
}

// Grid barrier with per-XCD L2 writeback (R7-proven, ~28us). Used exactly ONCE.
// After it, phase-A products (Q/INS/ES/betaP) are LLC-fresh and read via ld_*.
__device__ __forceinline__ void gsync(uint32* C, int bid) {
    __syncthreads();
    if (threadIdx.x == 0) {
        uint32* grp = C + (bid & 7) * 16;
        uint32* Rar = C + 128;
        uint32* Fc  = C + 144;
        uint32* rel = C + 256 + (bid & 7) * 16;
        int sp;
        uint32 old = __hip_atomic_fetch_add(grp, 1u, __ATOMIC_RELAXED, __HIP_MEMORY_SCOPE_AGENT);
        if (old == 35u)
            __hip_atomic_fetch_add(Rar, 36u, __ATOMIC_RELAXED, __HIP_MEMORY_SCOPE_AGENT);
        if (bid < 32) {
            sp = 0;
            while (__hip_atomic_load(Rar, __ATOMIC_RELAXED, __HIP_MEMORY_SCOPE_AGENT) < (uint32)GRID) {
                __builtin_amdgcn_s_sleep(2);
                if (++sp > SPIN_CAP) break;
            }
            __builtin_amdgcn_fence(__ATOMIC_RELEASE, "agent");  // buffer_wbl2 (own XCD)
            __builtin_amdgcn_s_waitcnt(0);
            __hip_atomic_fetch_add(Fc, 1u, __ATOMIC_RELAXED, __HIP_MEMORY_SCOPE_AGENT);
        }
        if (bid == 0) {
            sp = 0;
            while (__hip_atomic_load(Fc, __ATOMIC_RELAXED, __HIP_MEMORY_SCOPE_AGENT) < 32u) {
                __builtin_amdgcn_s_sleep(2);
                if (++sp > SPIN_CAP) break;
            }
            #pragma unroll
            for (int g2 = 0; g2 < 8; g2++)
                __hip_atomic_store(C + 256 + g2 * 16, 1u, __ATOMIC_RELAXED, __HIP_MEMORY_SCOPE_AGENT);
        }
        sp = 0;
        while (__hip_atomic_load(rel, __ATOMIC_RELAXED, __HIP_MEMORY_SCOPE_AGENT) == 0u) {
            __builtin_amdgcn_s_sleep(2);
            if (++sp > SPIN_CAP) break;
        }
    }
    __syncthreads();
}

__global__ __launch_bounds__(256, 2) void k_fused(
    const float* __restrict__ seq, const float* __restrict__ W_mem,
    const float* __restrict__ W_q, const float* __restrict__ W_kv,
    const float* __restrict__ W_mom, const float* __restrict__ W_step,
    const float* __restrict__ W_decay, float* __restrict__ out, void* ws)
{
    // 17696 floats = 70784 B -> 2 blocks/CU (141.5KB <= 160KB), 512 >= 288 co-resident
    __shared__ __align__(16) float smem[17696];
    const int bid = blockIdx.x;
    const int tid = threadIdx.x;

    uint32* C    = (uint32*)ws;           // grid-barrier counters (memset 0 per launch)
    float* base  = (float*)ws + 4096;     // data region starts at 16KB
    float* Q     = base;                  // N*D
    float* INS   = Q + ND;                // 4*N*D
    float* ES    = INS + 4 * ND;          // 4*N*D
    float* betaP = ES + 4 * ND;           // 2*N*N (split-2 slabs)

    // =========== PHASE A (unchanged from R7-proven): token fwd+bwd || scan+betamm ===========
    if (bid < 256) {
        const int h = tid >> 7, j = tid & 127;
        const int t = bid * 2 + h;
        float* s_seq = smem;            // [2][128]
        float* s_v   = smem + 256;      // [2][128]
        float* s_cur = smem + 512;      // [2][128]
        float* s_h   = smem + 768;      // [4][2][128]
        float* s_red = smem + 1792;     // [4 waves]
        float* s_lr  = smem + 1800;     // [2]
        float x = seq[t * D + j];
        s_seq[h * 128 + j] = x;
        float p0 = x * W_step[j];
        #pragma unroll
        for (int off = 32; off > 0; off >>= 1) p0 += __shfl_down(p0, off);
        if ((tid & 63) == 0) s_red[tid >> 6] = p0;
        __syncthreads();
        if (tid < 2) s_lr[tid] = s_red[2 * tid] + s_red[2 * tid + 1];
        float kp = 0.f, vp = 0.f, qp = 0.f;
        #pragma unroll 4
        for (int i = 0; i < D; i++) {
            float si = s_seq[h * 128 + i];
            kp += si * W_kv[i * 256 + j];
            vp += si * W_kv[i * 256 + 128 + j];
            qp += si * W_q[i * 128 + j];
        }
        s_cur[h * 128 + j] = kp;
        INS[t * D + j] = kp;
        s_v[h * 128 + j] = vp;
        Q[t * D + j] = qp;
        __syncthreads();
        for (int l = 0; l < 4; l++) {
            const float* Wl = W_mem + l * DD;
            float y0 = 0.f, y1 = 0.f;
            #pragma unroll 4
            for (int i = 0; i < D; i += 2) {
                y0 += s_cur[h * 128 + i]     * Wl[i * D + j];
                y1 += s_cur[h * 128 + i + 1] * Wl[(i + 1) * D + j];
            }
            float y = y0 + y1;
            __syncthreads();
            s_h[l * 256 + h * 128 + j] = y;
            if (l < 3) {
                float a = y * sigmoidf_(y);
                s_cur[h * 128 + j] = a;
                INS[(l + 1) * ND + t * D + j] = a;
            }
            __syncthreads();
        }
        float e = -s_lr[h] * (2.f / (float)D) * (s_h[3 * 256 + h * 128 + j] - s_v[h * 128 + j]);
        ES[3 * ND + t * D + j] = e;
        s_cur[h * 128 + j] = e;
        __syncthreads();
        for (int l = 3; l >= 1; l--) {
            const float* Wrow = W_mem + l * DD + j * D;
            float g0 = 0.f, g1 = 0.f;
            #pragma unroll 8
            for (int i4 = 0; i4 < D; i4 += 4) {
                float4 w = *(const float4*)(Wrow + i4);
                g0 += s_cur[h * 128 + i4]     * w.x + s_cur[h * 128 + i4 + 1] * w.y;
                g1 += s_cur[h * 128 + i4 + 2] * w.z + s_cur[h * 128 + i4 + 3] * w.w;
            }
            float g = g0 + g1;
            float hh = s_h[(l - 1) * 256 + h * 128 + j];
            float sg = sigmoidf_(hh);
            float e2 = g * (sg * (1.f + hh * (1.f - sg)));
            ES[(l - 1) * ND + t * D + j] = e2;
            __syncthreads();
            s_cur[h * 128 + j] = e2;
            __syncthreads();
        }
        __syncthreads();
    }

    if (bid < 272) {
        double* lA = (double*)smem;
        double* lD = lA + 512;
        int*    nC = (int*)(lD + 512);
        float*  sA  = smem + 2560;           // [32][34]
        float*  sDT = smem + 3648;           // [32][34] transposed
        __syncthreads();
        #pragma unroll
        for (int h2 = 0; h2 < 2; h2++) {
            int t = tid + h2 * 256;
            const float* sp = seq + t * D;
            float aa = 0.f, dd = 0.f;
            #pragma unroll 8
            for (int i4 = 0; i4 < D; i4 += 4) {
                float4 s4 = *(const float4*)(sp + i4);
                float4 wm = *(const float4*)(W_mom + i4);
                float4 wd = *(const float4*)(W_decay + i4);
                aa += s4.x * wm.x + s4.y * wm.y + s4.z * wm.z + s4.w * wm.w;
                dd += s4.x * wd.x + s4.y * wd.y + s4.z * wd.z + s4.w * wd.w;
            }
            float d = 1.f - sigmoidf_(dd);
            lA[t] = log((double)fmaxf(fabsf(aa), 1e-38f));
            lD[t] = log((double)fmaxf(d, 1e-38f));
            nC[t] = (aa < 0.f) ? 1 : 0;
        }
        __syncthreads();
        for (int off = 1; off < N; off <<= 1) {
            int k0 = tid, k1 = tid + 256;
            double va0 = 0., vd0 = 0., va1 = 0., vd1 = 0.;
            int vn0 = 0, vn1 = 0;
            if (k0 >= off) { va0 = lA[k0 - off]; vd0 = lD[k0 - off]; vn0 = nC[k0 - off]; }
            if (k1 >= off) { va1 = lA[k1 - off]; vd1 = lD[k1 - off]; vn1 = nC[k1 - off]; }
            __syncthreads();
            lA[k0] += va0; lD[k0] += vd0; nC[k0] += vn0;
            lA[k1] += va1; lD[k1] += vd1; nC[k1] += vn1;
            __syncthreads();
        }

        int slot = bid;
        if (bid >= 256) slot = bid - 16;
        else if (bid >= 240) slot = bid + 16;
        int pid = slot >> 1, zz = slot & 1;
        int bt = 0;
        while (pid >= bt + 1) { pid -= bt + 1; bt++; }
        int bs = pid;
        const int span = bt - bs + 1;
        const int chunk = (span + 1) >> 1;
        const int kBeg = bs + zz * chunk;
        const int kEnd = (kBeg + chunk < bt + 1) ? (kBeg + chunk) : (bt + 1);

        const int tx = tid & 15, ty = tid >> 4;
        float acc00 = 0.f, acc01 = 0.f, acc10 = 0.f, acc11 = 0.f;
        for (int kt = kBeg; kt < kEnd; kt++) {
            for (int i = tid; i < 1024; i += 256) {
                int rr = i >> 5, c = i & 31;
                int u = kt * 32 + rr, s2 = bs * 32 + c;
                float va = 0.f;
                if (s2 <= u) {
                    va = expf((float)(lA[u] - lA[s2]));
                    if ((nC[u] - nC[s2]) & 1) va = -va;
                }
                sA[rr * 34 + c] = va;
                int tt = bt * 32 + rr, kk = kt * 32 + c;
                float vd = 0.f;
                if (kk <= tt) vd = expf((float)(lD[tt] - lD[kk]));
                sDT[c * 34 + rr] = vd;
            }
            __syncthreads();
            #pragma unroll 8
            for (int k = 0; k < 32; k++) {
                float2 a = *(float2*)&sA[k * 34 + 2 * tx];
                float2 d = *(float2*)&sDT[k * 34 + 2 * ty];
                acc00 += d.x * a.x; acc01 += d.x * a.y;
                acc10 += d.y * a.x; acc11 += d.y * a.y;
            }
            __syncthreads();
        }
        float* bp = betaP + zz * NN + (bt * 32 + 2 * ty) * N + bs * 32 + 2 * tx;
        *(float2*)bp       = make_float2(acc00, acc01);
        *(float2*)(bp + N) = make_float2(acc10, acc11);
    }

    gsync(C, bid);   // the ONLY grid barrier: publishes Q, INS, ES, betaP to LLC

    // =========== PHASE B: fully block-local 4-layer chain (128 blocks x 4 tokens) ===========
    // Per token t: P_l[t] = X_l[t]@W_l + sum_s (X_l[t].INS_l[s]) * beta[t,s] * ES_l[s];
    // X_{l+1} = silu(P_l); out = P_3. No cross-block data -> no more barriers.
    if (bid < 128) {
        const int b = bid;
        const int tq = tid >> 7;          // 0..1 -> tokens tq, tq+2
        const int j  = tid & 127;
        const int nch = ((4 * b + 3) >> 6) + 1;   // chunks needed (triangle skip)
        float* sX  = smem;                // 4 x 132
        float* scb = smem + 528;          // 4 x 68
        float* sI  = smem + 800;          // 64 x 132
        float* sE  = smem + 9248;         // 64 x 132
        float accP0 = 0.f, accP1 = 0.f;

        for (int l = 0; l < 4; l++) {
            const float* INSl = INS + l * ND;
            const float* ESl  = ES + l * ND;
            const float* Wl   = W_mem + l * DD;
            __syncthreads();   // prev layer's LDS reads done
            if (l == 0) {
                if (tid < 128) {
                    float4 v = ld_f4(Q + b * 512 + tid * 4);
                    *(float4*)(sX + (tid >> 5) * 132 + (tid & 31) * 4) = v;
                }
            } else {
                sX[tq * 132 + j]       = accP0 * sigmoidf_(accP0);
                sX[(tq + 2) * 132 + j] = accP1 * sigmoidf_(accP1);
            }
            __syncthreads();
            // W-term: acc = X @ W_l  (W is a read-only input: plain cached loads, j-coalesced)
            float a0 = 0.f, a1 = 0.f;
            #pragma unroll 4
            for (int k = 0; k < 128; k++) {
                float w = Wl[k * 128 + j];
                a0 += sX[tq * 132 + k] * w;
                a1 += sX[(tq + 2) * 132 + k] * w;
            }
            accP0 = a0; accP1 = a1;
            // 64-wide s-chunks of the rank-1 sum
            for (int ci = 0; ci < nch; ci++) {
                #pragma unroll
                for (int i = 0; i < 8; i++) {
                    int f4 = tid + 256 * i;
                    int row = f4 >> 5, c4 = f4 & 31;
                    float4 vi = ld_f4(INSl + ci * 8192 + f4 * 4);
                    *(float4*)(sI + row * 132 + c4 * 4) = vi;
                    float4 ve = ld_f4(ESl + ci * 8192 + f4 * 4);
                    *(float4*)(sE + row * 132 + c4 * 4) = ve;
                }
                __syncthreads();
                // GEMM1: c[t2][s] = X[t2].INS[s], fold masked beta (issue beta loads first)
                {
                    const int t2 = tid >> 6, s = tid & 63;
                    const int row = 4 * b + t2, sg = ci * 64 + s;
                    float bv = 0.f;
                    if (sg <= row)
                        bv = ld_f(betaP + row * N + sg) + ld_f(betaP + NN + row * N + sg);
                    float c0 = 0.f, c1 = 0.f;
                    #pragma unroll 8
                    for (int k4 = 0; k4 < 128; k4 += 8) {
                        float4 x0 = *(float4*)(sX + t2 * 132 + k4);
                        float4 q0 = *(float4*)(sI + s * 132 + k4);
                        float4 x1 = *(float4*)(sX + t2 * 132 + k4 + 4);
                        float4 q1 = *(float4*)(sI + s * 132 + k4 + 4);
                        c0 += x0.x*q0.x + x0.y*q0.y + x0.z*q0.z + x0.w*q0.w;
                        c1 += x1.x*q1.x + x1.y*q1.y + x1.z*q1.z + x1.w*q1.w;
                    }
                    scb[t2 * 68 + s] = (c0 + c1) * bv;
                }
                __syncthreads();
                // GEMM2: acc[t][j] += sum_s cb[t][s] * ES[s][j]
                {
                    const float* c0p = scb + tq * 68;
                    const float* c1p = scb + (tq + 2) * 68;
                    float b0 = accP0, b1 = accP1;
                    #pragma unroll 8
                    for (int s = 0; s < 64; s++) {
                        float ev = sE[s * 132 + j];
                        b0 += c0p[s] * ev;
                        b1 += c1p[s] * ev;
                    }
                    accP0 = b0; accP1 = b1;
                }
                __syncthreads();   // scb/sI/sE reuse next chunk
            }
        }
        // final layer output: no activation
        out[(4 * b + tq) * 128 + j]     = accP0;
        out[(4 * b + tq + 2) * 128 + j] = accP1;
    }
}

extern "C" void kernel_launch(void* const* d_in, const int* in_sizes, int n_in,
                              void* d_out, int out_size, void* d_ws, size_t ws_size,
                              hipStream_t stream) {
    // zero the grid-barrier counter region (graph memset node; data starts at 16KB)
    (void)hipMemsetAsync(d_ws, 0, 16384, stream);
    hipLaunchKernelGGL(k_fused, dim3(GRID), dim3(256), 0, stream,
        (const float*)d_in[0], (const float*)d_in[1], (const float*)d_in[2],
        (const float*)d_in[3], (const float*)d_in[4], (const float*)d_in[5],
        (const float*)d_in[6], (float*)d_out, d_ws);
}